// Round 11
// baseline (2009.645 us; speedup 1.0000x reference)
//
#include <hip/hip_runtime.h>
#include <math.h>

#define B_ 128
#define T_ 100
#define RS 72      // padded row stride (words) for full-width kernels
#define RS2 40     // f-split row stride: [0..2] zero, [3] halo-L, [4..35] own, [36] halo-R, [37..39] zero

// ---------------------------------------------------------------------------
// Fast transcendentals (~1e-6 rel err; threshold 1.27e-4)
// ---------------------------------------------------------------------------
__device__ __forceinline__ float frcp_(float x){ return __builtin_amdgcn_rcpf(x); }
__device__ __forceinline__ float fsig_(float x){ return frcp_(1.f + __expf(-x)); }
__device__ __forceinline__ float ftanh_(float x){ float e = __expf(2.f*x); return 1.f - 2.f*frcp_(e+1.f); }
__device__ __forceinline__ float gate1(float zi, float zf, float zo, float zg, float& c){
    float cc = fsig_(zf)*c + fsig_(zi)*ftanh_(zg);
    c = cc;
    return fsig_(zo)*ftanh_(cc);
}
__device__ __forceinline__ float4 ldf4(const float* p){ return *reinterpret_cast<const float4*>(p); }
__device__ __forceinline__ void stf4(float* p, float4 v){ *reinterpret_cast<float4*>(p) = v; }
__device__ __forceinline__ float2 ldf2(const float* p){ return *reinterpret_cast<const float2*>(p); }
__device__ __forceinline__ void stf2(float* p, float2 v){ *reinterpret_cast<float2*>(p) = v; }
__device__ __forceinline__ float4 add4(float4 a, float4 b){
    return make_float4(a.x+b.x, a.y+b.y, a.z+b.z, a.w+b.w);
}
__device__ __forceinline__ float4 gate4(float4 zi, float4 zf, float4 zo, float4 zg,
                                        float bi, float bf, float bo, float bg, float4& c){
    float4 h;
    h.x = gate1(zi.x+bi, zf.x+bf, zo.x+bo, zg.x+bg, c.x);
    h.y = gate1(zi.y+bi, zf.y+bf, zo.y+bo, zg.y+bg, c.y);
    h.z = gate1(zi.z+bi, zf.z+bf, zo.z+bo, zg.z+bg, c.z);
    h.w = gate1(zi.w+bi, zf.w+bf, zo.w+bo, zg.w+bg, c.w);
    return h;
}

__device__ __forceinline__ void fma4v(float w, float u0,float u1,float u2,float u3, float4& a){
    a.x = fmaf(w,u0,a.x); a.y = fmaf(w,u1,a.y);
    a.z = fmaf(w,u2,a.z); a.w = fmaf(w,u3,a.w);
}
__device__ __forceinline__ void fma2v(float w, float u0,float u1, float2& a){
    a.x = fmaf(w,u0,a.x); a.y = fmaf(w,u1,a.y);
}

// ---------------------------------------------------------------------------
// Row accumulators, weights from LDS.
// CURRENCY MODEL (amended round-8/9): below LDS-pipe saturation these kernels
// are LATENCY-bound -> waves/CU is the lever (proven: enc 838->781, decg
// similar at 8->16 waves). Barrier-paced: per-step time ~ max over groups
// (round-11: rebalance rows so groups are even). LDS LAYOUT RULE (round-7):
// partial buffers lane-contiguous. Do NOT hoist weights to VGPRs (round-2).
// ---------------------------------------------------------------------------
template<int ROWS>
__device__ __forceinline__ void rowacc4(const float* __restrict__ rowp,
                                        const float* __restrict__ wk,
                                        float4& ai, float4& af, float4& ao, float4& ag)
{
    float  m = rowp[-1];
    float4 a = ldf4(rowp);
    float  p = rowp[4];
    float4 wa = ldf4(wk);
    float4 wb = ldf4(wk + ROWS);
    float4 wc = ldf4(wk + 2*ROWS);
    fma4v(wa.x, m,a.x,a.y,a.z, ai);  fma4v(wa.y, m,a.x,a.y,a.z, af);
    fma4v(wa.z, m,a.x,a.y,a.z, ao);  fma4v(wa.w, m,a.x,a.y,a.z, ag);
    fma4v(wb.x, a.x,a.y,a.z,a.w, ai); fma4v(wb.y, a.x,a.y,a.z,a.w, af);
    fma4v(wb.z, a.x,a.y,a.z,a.w, ao); fma4v(wb.w, a.x,a.y,a.z,a.w, ag);
    fma4v(wc.x, a.y,a.z,a.w,p, ai);  fma4v(wc.y, a.y,a.z,a.w,p, af);
    fma4v(wc.z, a.y,a.z,a.w,p, ao);  fma4v(wc.w, a.y,a.z,a.w,p, ag);
}
template<int ROWS>
__device__ __forceinline__ void rowacc2(const float* __restrict__ rowp,
                                        const float* __restrict__ wk,
                                        float2& ai, float2& af, float2& ao, float2& ag)
{
    float  m = rowp[-1];
    float2 a = *reinterpret_cast<const float2*>(rowp);
    float  p = rowp[2];
    float4 wa = ldf4(wk);
    float4 wb = ldf4(wk + ROWS);
    float4 wc = ldf4(wk + 2*ROWS);
    fma2v(wa.x, m,a.x, ai); fma2v(wa.y, m,a.x, af);
    fma2v(wa.z, m,a.x, ao); fma2v(wa.w, m,a.x, ag);
    fma2v(wb.x, a.x,a.y, ai); fma2v(wb.y, a.x,a.y, af);
    fma2v(wb.z, a.x,a.y, ao); fma2v(wb.w, a.x,a.y, ag);
    fma2v(wc.x, a.y,p, ai); fma2v(wc.y, a.y,p, af);
    fma2v(wc.z, a.y,p, ao); fma2v(wc.w, a.y,p, ag);
}
template<int ROWS>
__device__ __forceinline__ void rowacc8(const float* __restrict__ rowp,
                                        const float* __restrict__ wk,
                                        float4& i0, float4& i1, float4& f0v, float4& f1v,
                                        float4& o0, float4& o1, float4& g0, float4& g1)
{
    float  m = rowp[-1];
    float4 a = ldf4(rowp);
    float4 b = ldf4(rowp + 4);
    float  p = rowp[8];
    float4 wa = ldf4(wk);
    float4 wb = ldf4(wk + ROWS);
    float4 wc = ldf4(wk + 2*ROWS);
    fma4v(wa.x, m,a.x,a.y,a.z, i0);   fma4v(wa.x, a.w,b.x,b.y,b.z, i1);
    fma4v(wa.y, m,a.x,a.y,a.z, f0v);  fma4v(wa.y, a.w,b.x,b.y,b.z, f1v);
    fma4v(wa.z, m,a.x,a.y,a.z, o0);   fma4v(wa.z, a.w,b.x,b.y,b.z, o1);
    fma4v(wa.w, m,a.x,a.y,a.z, g0);   fma4v(wa.w, a.w,b.x,b.y,b.z, g1);
    fma4v(wb.x, a.x,a.y,a.z,a.w, i0); fma4v(wb.x, b.x,b.y,b.z,b.w, i1);
    fma4v(wb.y, a.x,a.y,a.z,a.w, f0v);fma4v(wb.y, b.x,b.y,b.z,b.w, f1v);
    fma4v(wb.z, a.x,a.y,a.z,a.w, o0); fma4v(wb.z, b.x,b.y,b.z,b.w, o1);
    fma4v(wb.w, a.x,a.y,a.z,a.w, g0); fma4v(wb.w, b.x,b.y,b.z,b.w, g1);
    fma4v(wc.x, a.y,a.z,a.w,b.x, i0); fma4v(wc.x, b.y,b.z,b.w,p, i1);
    fma4v(wc.y, a.y,a.z,a.w,b.x, f0v);fma4v(wc.y, b.y,b.z,b.w,p, f1v);
    fma4v(wc.z, a.y,a.z,a.w,b.x, o0); fma4v(wc.z, b.y,b.z,b.w,p, o1);
    fma4v(wc.w, a.y,a.z,a.w,b.x, g0); fma4v(wc.w, b.y,b.z,b.w,p, g1);
}

// ---------------------------------------------------------------------------
// Encoder, f-split block pairs, 1024 threads (round-9, 768 us). Round-11:
// L1 rows rebalanced 14/14/10/10 across g0..g3 (L0 stays g2/g3) so per-lane
// P1 work is even (max 792 -> 696 FMA); barY paces on the slowest group.
// ---------------------------------------------------------------------------
__global__ __launch_bounds__(1024, 4) void enc_kernel(
    const float* __restrict__ x,
    const float* __restrict__ w0, const float* __restrict__ b0,
    const float* __restrict__ w1, const float* __restrict__ b1,
    float* __restrict__ seq,
    float* __restrict__ h1f, float* __restrict__ c1f,
    float* __restrict__ h2f, float* __restrict__ c2f,
    float* __restrict__ comm, int* __restrict__ flags)
{
    __shared__ float wl0[51 * 64];     // k=(ci*3+d), ci<17, col=ch*4+g (CH=16)
    __shared__ float wl1[144 * 128];   // ci<48 (0..15 = h0, 16..47 = h1)
    __shared__ float bs0[64];
    __shared__ float bs1[128];
    __shared__ float hbuf[50 * RS2];   // rows 0,1 = x dbuf; 2..17 h0; 18..49 h1
    __shared__ float zsA[2048];        // L0 partial (g3): q*512 + 2*r
    __shared__ float zsB3[3 * 4096];   // L1 partials (g1..3): set*4096 + q*1024 + 4*r

    const int tid = threadIdx.x;
    const int b = blockIdx.x & 127;
    const int s = blockIdx.x >> 7;
    const int gofs = s << 5;
    const int g  = tid >> 8;            // row-group 0..3
    const int r  = tid & 255;
    const int chB = r >> 3, f0B = (r & 7) * 4;    // L1: 32ch x 8 tiles, FT=4
    const int chA = r >> 4, f0A = (r & 15) * 2;   // L0: 16ch x 16 tiles, FT=2
    // L1 row ranges: g0/g1 take 14 rows, g2/g3 take 10 (they also run L0)
    const int nL1 = (g < 2) ? 14 : 10;
    const int rloL1 = (g < 2) ? 14 * g : 28 + 10 * (g - 2);
    const int haloSlot = s ? 3 : 36;
    const int myId = (b << 1) | s;
    const int peerId = myId ^ 1;
    float* mySend = &comm[(size_t)myId * 128];         // [par][64]: 0..31 h1, 32..47 h0
    const float* peerBuf = &comm[(size_t)peerId * 128];

    for (int idx = tid; idx < 51 * 64; idx += 1024) {
        int k = idx >> 6, rr = idx & 63;
        int ch = rr >> 2, gg = rr & 3;
        int ci = k / 3, d = k - ci * 3;
        wl0[idx] = w0[((gg * 16 + ch) * 17 + ci) * 9 + d * 3 + 1];
    }
    for (int idx = tid; idx < 144 * 128; idx += 1024) {
        int k = idx >> 7, rr = idx & 127;
        int ch = rr >> 2, gg = rr & 3;
        int ci = k / 3, d = k - ci * 3;
        wl1[idx] = w1[((gg * 32 + ch) * 48 + ci) * 9 + d * 3 + 1];
    }
    if (tid < 64) bs0[tid] = b0[tid];
    if (tid < 128) bs1[tid] = b1[tid];
    for (int i = tid; i < 50 * RS2; i += 1024) hbuf[i] = 0.f;
    __syncthreads();

    const int xl = tid - 256;           // g1 threads 256-289 stage x (34 cols)
    if (xl >= 0 && xl < 34) {
        const int gc = gofs - 1 + xl;
        const bool v = (gc >= 0) && (gc < 64);
        hbuf[0 * RS2 + 3 + xl] = v ? x[(b * T_ + 0) * 64 + gc] : 0.f;
        hbuf[1 * RS2 + 3 + xl] = v ? x[(b * T_ + 1) * 64 + gc] : 0.f;
    }
    const float biA = bs0[chA], bfA = bs0[16+chA], boA = bs0[32+chA], bgA = bs0[48+chA];
    const float biB = bs1[chB], bfB = bs1[32+chB], boB = bs1[64+chB], bgB = bs1[96+chB];
    __syncthreads();

    const float4 z4 = make_float4(0.f, 0.f, 0.f, 0.f);
    const float2 z2 = make_float2(0.f, 0.f);
    float2 c0q = z2;                    // L0 cell (g2, 2 cols)
    float4 c1a = z4;                    // L1 cell (g0, 4 cols)

    // ---- prologue: L0(0) from x(0); h0 rows zero so g3 partial is zero ----
    if (g == 2) {
        float2 ai = z2, af = z2, ao = z2, ag = z2;
        rowacc2<64>(&hbuf[0 * RS2 + 4 + f0A], &wl0[chA * 4], ai, af, ao, ag);
        float2 hq;
        hq.x = gate1(ai.x + biA, af.x + bfA, ao.x + boA, ag.x + bgA, c0q.x);
        hq.y = gate1(ai.y + biA, af.y + bfA, ao.y + boA, ag.y + bgA, c0q.y);
        *reinterpret_cast<float2*>(&hbuf[(2 + chA) * RS2 + 4 + f0A]) = hq;
        if ((r & 15) == (s ? 0 : 15)) {            // boundary column owner
            const float v = s ? hq.x : hq.y;
            __hip_atomic_store((unsigned int*)&mySend[1 * 64 + 32 + chA],
                               __float_as_uint(v),
                               __ATOMIC_RELAXED, __HIP_MEMORY_SCOPE_AGENT);
        }
    }
    __syncthreads();   // drains vmcnt -> prologue payload globally visible

#pragma unroll 1
    for (int t = 0; t < T_; ++t) {
        // publish exchange n = t+1 (payload stored before the last barrier)
        if (tid == 0)
            __hip_atomic_store(&flags[myId], t + 1,
                               __ATOMIC_RELAXED, __HIP_MEMORY_SCOPE_AGENT);
        // import partner halo column(s): h1(t-1) [tid<32], h0(t) [tid 32..47]
        if (tid < 48 && (t > 0 || tid >= 32)) {
            while (__hip_atomic_load(&flags[peerId],
                                     __ATOMIC_ACQUIRE, __HIP_MEMORY_SCOPE_AGENT) < t + 1)
                __builtin_amdgcn_s_sleep(2);
            const int par = (t + 1) & 1;
            const unsigned int uv =
                __hip_atomic_load((const unsigned int*)&peerBuf[par * 64 + tid],
                                  __ATOMIC_RELAXED, __HIP_MEMORY_SCOPE_AGENT);
            const float v = __uint_as_float(uv);
            if (tid < 32) hbuf[(18 + tid) * RS2 + haloSlot] = v;
            else          hbuf[(2 + (tid - 32)) * RS2 + haloSlot] = v;
        }
        __syncthreads();                                   // bar0

        const bool doL0 = (t + 1 < T_);
        // ================= P1: accumulate =================
        float4 I = z4, F = z4, O = z4, G = z4;             // L1(t), 4 cols
#pragma unroll 1
        for (int j = 0; j < nL1; ++j) {
            const int ci = rloL1 + j;
            rowacc4<128>(&hbuf[(2 + ci) * RS2 + 4 + f0B],
                         &wl1[(ci * 3) * 128 + chB * 4], I, F, O, G);
        }
        float2 ai = z2, af = z2, ao = z2, ag = z2;         // L0(t+1), 2 cols
        if (doL0) {
            if (g == 2) {
                rowacc2<64>(&hbuf[((t + 1) & 1) * RS2 + 4 + f0A], &wl0[chA * 4],
                            ai, af, ao, ag);
#pragma unroll 1
                for (int j = 0; j < 8; ++j)
                    rowacc2<64>(&hbuf[(2 + j) * RS2 + 4 + f0A],
                                &wl0[((1 + j) * 3) * 64 + chA * 4], ai, af, ao, ag);
            } else if (g == 3) {
#pragma unroll 1
                for (int j = 8; j < 16; ++j)
                    rowacc2<64>(&hbuf[(2 + j) * RS2 + 4 + f0A],
                                &wl0[((1 + j) * 3) * 64 + chA * 4], ai, af, ao, ag);
            }
        }
        if (g != 0) {                   // L1 partial -> zsB3 (lane-contiguous 4r)
            float* zp = &zsB3[(g - 1) * 4096 + r * 4];
            stf4(zp, I); stf4(zp + 1024, F); stf4(zp + 2048, O); stf4(zp + 3072, G);
        }
        if (g == 3 && doL0) {           // L0 partial -> zsA (lane-contiguous 2r)
            float* zp = &zsA[r * 2];
            stf2(zp, ai); stf2(zp + 512, af); stf2(zp + 1024, ao); stf2(zp + 1536, ag);
        }
        if (xl >= 0 && xl < 34 && t + 2 < T_) {            // g1 stages x(t+2)
            const int gc = gofs - 1 + xl;
            hbuf[(t & 1) * RS2 + 3 + xl] =
                (gc >= 0 && gc < 64) ? x[(b * T_ + t + 2) * 64 + gc] : 0.f;
        }
        __syncthreads();                                   // barY
        // ================= P2: combine + gates + send =================
        if (g == 0) {                                      // L1 combine (FT=4)
            const float* p0 = &zsB3[0 * 4096 + r * 4];
            const float* p1 = &zsB3[1 * 4096 + r * 4];
            const float* p2 = &zsB3[2 * 4096 + r * 4];
            float4 zi = add4(add4(I, ldf4(p0)),        add4(ldf4(p1),        ldf4(p2)));
            float4 zf = add4(add4(F, ldf4(p0 + 1024)), add4(ldf4(p1 + 1024), ldf4(p2 + 1024)));
            float4 zo = add4(add4(O, ldf4(p0 + 2048)), add4(ldf4(p1 + 2048), ldf4(p2 + 2048)));
            float4 zg = add4(add4(G, ldf4(p0 + 3072)), add4(ldf4(p1 + 3072), ldf4(p2 + 3072)));
            float4 hq = gate4(zi, zf, zo, zg, biB, bfB, boB, bgB, c1a);
            stf4(&hbuf[(18 + chB) * RS2 + 4 + f0B], hq);
            stf4(&seq[((size_t)t * B_ + b) * 2048 + chB * 64 + gofs + f0B], hq);
            if (doL0 && (r & 7) == (s ? 0 : 7)) {          // h1 boundary col
                const float v = s ? hq.x : hq.w;
                __hip_atomic_store((unsigned int*)&mySend[(t & 1) * 64 + chB],
                                   __float_as_uint(v),
                                   __ATOMIC_RELAXED, __HIP_MEMORY_SCOPE_AGENT);
            }
        }
        if (g == 2 && doL0) {                              // L0 combine (FT=2)
            float2 pzi = ldf2(&zsA[r * 2]);
            float2 pzf = ldf2(&zsA[512 + r * 2]);
            float2 pzo = ldf2(&zsA[1024 + r * 2]);
            float2 pzg = ldf2(&zsA[1536 + r * 2]);
            float2 hq2;
            hq2.x = gate1(ai.x+pzi.x+biA, af.x+pzf.x+bfA, ao.x+pzo.x+boA, ag.x+pzg.x+bgA, c0q.x);
            hq2.y = gate1(ai.y+pzi.y+biA, af.y+pzf.y+bfA, ao.y+pzo.y+boA, ag.y+pzg.y+bgA, c0q.y);
            *reinterpret_cast<float2*>(&hbuf[(2 + chA) * RS2 + 4 + f0A]) = hq2;
            if ((r & 15) == (s ? 0 : 15)) {
                const float v = s ? hq2.x : hq2.y;
                __hip_atomic_store((unsigned int*)&mySend[(t & 1) * 64 + 32 + chA],
                                   __float_as_uint(v),
                                   __ATOMIC_RELAXED, __HIP_MEMORY_SCOPE_AGENT);
            }
        }
        __syncthreads();                                   // barZ (drains sends)
    }

    // final states: L0 on g2 threads (FT=2), L1 on g0 threads (FT=4)
    if (g == 2) {
        *reinterpret_cast<float2*>(&h1f[(b * 16 + chA) * 64 + gofs + f0A]) =
            *reinterpret_cast<const float2*>(&hbuf[(2 + chA) * RS2 + 4 + f0A]);
        *reinterpret_cast<float2*>(&c1f[(b * 16 + chA) * 64 + gofs + f0A]) = c0q;
    }
    if (g == 0) {
        stf4(&h2f[b * 2048 + chB * 64 + gofs + f0B],
             ldf4(&hbuf[(18 + chB) * RS2 + 4 + f0B]));
        stf4(&c2f[b * 2048 + chB * 64 + gofs + f0B], c1a);
    }
}

// ---------------------------------------------------------------------------
// xconv0: parallel x-part pre-activations for dec0. One block per (t,b).
// ---------------------------------------------------------------------------
__global__ __launch_bounds__(256, 2) void xconv0_kernel(
    const float* __restrict__ seqIn, const float* __restrict__ w,
    float* __restrict__ zx, int t0)
{
    __shared__ float wl[96 * 128];
    __shared__ float xt[32 * RS];

    const int tid = threadIdx.x;
    const int tl = blockIdx.x / B_;
    const int b  = blockIdx.x - tl * B_;
    const int t  = t0 + tl;

    for (int idx = tid; idx < 96 * 128; idx += 256) {
        int k = idx >> 7, rr = idx & 127;
        int ch = rr >> 2, g = rr & 3;
        int ci = k / 3, d = k - ci * 3;
        wl[idx] = w[((g * 32 + ch) * 64 + ci) * 9 + d * 3 + 1];
    }
    {
        int rr = tid >> 3, j = tid & 7;
        xt[rr * RS + (j < 4 ? j : 64 + j)] = 0.f;
    }
    {
        const float* s = &seqIn[((size_t)t * B_ + b) * 2048 + tid * 8];
        float4 v0 = ldf4(s);
        float4 v1 = ldf4(s + 4);
        int ci = tid >> 3, col = (tid & 7) * 8;
        stf4(&xt[ci * RS + 4 + col], v0);
        stf4(&xt[ci * RS + 4 + col + 4], v1);
    }
    __syncthreads();

    const int ch = tid >> 3, f0 = (tid & 7) * 8;
    const float4 z4 = make_float4(0.f,0.f,0.f,0.f);
    float4 i0=z4,i1=z4,f0v=z4,f1v=z4,o0=z4,o1=z4,g0=z4,g1=z4;
#pragma unroll 1
    for (int rr = 0; rr < 32; ++rr)
        rowacc8<128>(&xt[rr * RS + 4 + f0], wl + (rr * 3) * 128 + ch * 4,
                     i0, i1, f0v, f1v, o0, o1, g0, g1);

    float* zp = &zx[(((size_t)tl * B_ + b) * 4) * 2048 + ch * 64 + f0];
    stf4(zp, i0);            stf4(zp + 4, i1);
    stf4(zp + 2048, f0v);    stf4(zp + 2048 + 4, f1v);
    stf4(zp + 4096, o0);     stf4(zp + 4096 + 4, o1);
    stf4(zp + 6144, g0);     stf4(zp + 6144 + 4, g1);
}

// ---------------------------------------------------------------------------
// decg: fused skewed decoder, f-split block pairs, 1024 threads (round-10).
// Phase u: dec0(u) AND dec1(u-1). dec0: tid 0-511, kg=2 x 256 lanes FT=4,
// 16 rows each, zs0 lane-contiguous. dec1: tid 512-1023, 4 groups x 128
// lanes FT=4, 12 rows each, zs1_3 lane-contiguous. UNCHANGED this round.
// ---------------------------------------------------------------------------
__global__ __launch_bounds__(1024, 4) void decg(
    const float* __restrict__ w0, const float* __restrict__ b0,
    const float* __restrict__ w1, const float* __restrict__ b1,
    const float* __restrict__ zx,
    const float* __restrict__ h0in, const float* __restrict__ c0in,
    const float* __restrict__ h1in, const float* __restrict__ c1in,
    float* __restrict__ h0sv, float* __restrict__ c0sv,
    float* __restrict__ h1sv, float* __restrict__ c1sv,
    const float* __restrict__ fw, const float* __restrict__ fb,
    float* __restrict__ out,
    float* __restrict__ comm0, float* __restrict__ comm1,
    int* __restrict__ flg, int t0, int tn, int lastc)
{
    __shared__ float wl0[96 * 128];    // dec0 h-rows only (w row 32+ci)
    __shared__ float wl1[144 * 64];    // dec1 x-rows (0..31) + h-rows (32..47)
    __shared__ float hp0[32 * RS2];
    __shared__ float hp1[16 * RS2];
    __shared__ float zs0[4096];        // dec0 partials (kg1): q*1024 + 4*r
    __shared__ float zs1_3[3 * 2048];  // dec1 partials: set*2048 + q*512 + 4*rg1
    __shared__ float bs0[128];
    __shared__ float bs1[64];
    __shared__ float fcw[16];
    __shared__ float fcb_s;

    const int tid = threadIdx.x;
    const int b = blockIdx.x & 127;
    const int s = blockIdx.x >> 7;
    const int gofs = s << 5;
    const int haloSlot = s ? 3 : 36;
    const int bcol = s ? 31 : 32;
    const int myId = (b << 1) | s, peerId = myId ^ 1;
    float* send0 = &comm0[(size_t)myId * 64];          // [par][32ch]
    const float* peer0 = &comm0[(size_t)peerId * 64];
    float* send1 = &comm1[(size_t)myId * 32];          // [par][16ch]
    const float* peer1 = &comm1[(size_t)peerId * 32];

    const bool isD0 = (tid < 512);
    const int sub = tid & 511;
    const int kg = sub >> 8;                           // dec0 half 0/1
    const int r = sub & 255;
    const int ch0 = r >> 3, t0f = (r & 7) * 4;        // dec0: 32ch x 8 tiles FT=4
    const int d1g = sub >> 7;                          // dec1 group 0..3
    const int rg1 = sub & 127;
    const int ch1 = rg1 >> 3, t1f = (rg1 & 7) * 4;    // dec1: 16ch x 8 tiles FT=4

    for (int idx = tid; idx < 96 * 128; idx += 1024) {
        int k = idx >> 7, rr = idx & 127;
        int c8 = rr >> 2, g = rr & 3;
        int ci = k / 3, d = k - ci * 3;
        wl0[idx] = w0[((g * 32 + c8) * 64 + 32 + ci) * 9 + d * 3 + 1];
    }
    for (int idx = tid; idx < 144 * 64; idx += 1024) {
        int k = idx >> 6, rr = idx & 63;
        int c8 = rr >> 2, g = rr & 3;
        int ci = k / 3, d = k - ci * 3;
        wl1[idx] = w1[((g * 16 + c8) * 48 + ci) * 9 + d * 3 + 1];
    }
    if (tid < 128) bs0[tid] = b0[tid];
    if (tid < 64) bs1[tid] = b1[tid];
    if (tid < 16) fcw[tid] = fw[tid];
    if (tid == 16) fcb_s = fb[0];
    for (int i = tid; i < 32 * RS2; i += 1024) hp0[i] = 0.f;
    for (int i = tid; i < 16 * RS2; i += 1024) hp1[i] = 0.f;
    __syncthreads();

    // restore states (own cols + boundary halo from peer's saved full-width h)
    {
        int c8 = tid >> 5, f = tid & 31;
        hp0[c8 * RS2 + 4 + f] = h0in[b * 2048 + c8 * 64 + gofs + f];
        if (tid < 512)
            hp1[(tid >> 5) * RS2 + 4 + (tid & 31)] =
                h1in[b * 1024 + (tid >> 5) * 64 + gofs + (tid & 31)];
    }
    if (tid < 32) hp0[tid * RS2 + haloSlot] = h0in[b * 2048 + tid * 64 + bcol];
    if (tid >= 64 && tid < 80)
        hp1[(tid - 64) * RS2 + haloSlot] = h1in[b * 1024 + (tid - 64) * 64 + bcol];

    const float4 z4 = make_float4(0.f, 0.f, 0.f, 0.f);
    float4 c0v = z4;                    // dec0 cell (kg0 & isD0, 4 cols)
    float4 c1v = z4;                    // dec1 cell (d1g==0)
    float bi, bfv, bo, bg;
    if (isD0) { bi = bs0[ch0]; bfv = bs0[32+ch0]; bo = bs0[64+ch0]; bg = bs0[96+ch0]; }
    else      { bi = bs1[ch1]; bfv = bs1[16+ch1]; bo = bs1[32+ch1]; bg = bs1[48+ch1]; }
    if (isD0 && kg == 0)
        c0v = ldf4(&c0in[b * 2048 + ch0 * 64 + gofs + t0f]);
    if (!isD0 && d1g == 0)
        c1v = ldf4(&c1in[b * 1024 + ch1 * 64 + gofs + t1f]);
    const float fcbv = fcb_s;

#pragma unroll 1
    for (int u = t0; u < t0 + tn + lastc; ++u) {
        // publish: my P2(u-1) payloads are visible (barZ drained vmcnt)
        if (tid == 0)
            __hip_atomic_store(&flg[myId], u,
                               __ATOMIC_RELAXED, __HIP_MEMORY_SCOPE_AGENT);
        if (u > t0) {
            const int par = (u - 1) & 1;
            if (tid < 32) {                         // h0(u-1) halo
                while (__hip_atomic_load(&flg[peerId],
                                         __ATOMIC_ACQUIRE, __HIP_MEMORY_SCOPE_AGENT) < u)
                    __builtin_amdgcn_s_sleep(2);
                hp0[tid * RS2 + haloSlot] = __uint_as_float(
                    __hip_atomic_load((const unsigned int*)&peer0[par * 32 + tid],
                                      __ATOMIC_RELAXED, __HIP_MEMORY_SCOPE_AGENT));
            } else if (tid >= 64 && tid < 80 && u >= 2) {   // h1(u-2) halo
                while (__hip_atomic_load(&flg[peerId],
                                         __ATOMIC_ACQUIRE, __HIP_MEMORY_SCOPE_AGENT) < u)
                    __builtin_amdgcn_s_sleep(2);
                hp1[(tid - 64) * RS2 + haloSlot] = __uint_as_float(
                    __hip_atomic_load((const unsigned int*)&peer1[par * 16 + (tid - 64)],
                                      __ATOMIC_RELAXED, __HIP_MEMORY_SCOPE_AGENT));
            }
        }
        __syncthreads();                                   // bar0

        const bool d0act = (u - t0 < tn);                  // u < t0+tn (=> u < T_)
        const bool d1act = (u >= 1);
        float4 ai = z4, af = z4, ao = z4, ag = z4;         // shared acc (FT=4)
        float4 xi = z4, xf = z4, xo = z4, xg = z4;         // zx prefetch (dec0 kg0)

        if (isD0) {
            if (d0act) {
                if (kg == 0) {
                    const float* zp = &zx[(((size_t)(u - t0) * B_ + b) * 4) * 2048
                                          + ch0 * 64 + gofs + t0f];
                    xi = ldf4(zp);
                    xf = ldf4(zp + 2048);
                    xo = ldf4(zp + 4096);
                    xg = ldf4(zp + 6144);
                }
#pragma unroll 1
                for (int j = 0; j < 16; ++j) {
                    const int ci = kg * 16 + j;
                    rowacc4<128>(&hp0[ci * RS2 + 4 + t0f], &wl0[(ci * 3) * 128 + ch0 * 4],
                                 ai, af, ao, ag);
                }
            }
            if (kg == 1 && r < 32 && u >= 2) {             // fc(u-2): hp1 = h1(u-2)
                float a = fcbv;
#pragma unroll
                for (int k2 = 0; k2 < 16; ++k2)
                    a = fmaf(fcw[k2], hp1[k2 * RS2 + 4 + r], a);
                out[(b * T_ + (u - 2)) * 64 + gofs + r] = a;
            }
        } else if (d1act) {
            const int rlo = 12 * d1g, rhi = rlo + 12;
            const int xhi = rhi < 32 ? rhi : 32;
            const int hlo = rlo > 32 ? rlo : 32;
#pragma unroll 1
            for (int rr = rlo; rr < xhi; ++rr)             // x rows (h0(u-1))
                rowacc4<64>(&hp0[rr * RS2 + 4 + t1f], &wl1[(rr * 3) * 64 + ch1 * 4],
                            ai, af, ao, ag);
#pragma unroll 1
            for (int rr = hlo; rr < rhi; ++rr)             // h rows (h1(u-2))
                rowacc4<64>(&hp1[(rr - 32) * RS2 + 4 + t1f], &wl1[(rr * 3) * 64 + ch1 * 4],
                            ai, af, ao, ag);
        }
        if (isD0) {
            if (kg == 1 && d0act) {                        // lane-contiguous r*4
                float* zp = &zs0[r * 4];
                stf4(zp, ai); stf4(zp + 1024, af);
                stf4(zp + 2048, ao); stf4(zp + 3072, ag);
            }
        } else if (d1g != 0 && d1act) {                    // lane-contiguous rg1*4
            float* zp = &zs1_3[(d1g - 1) * 2048 + rg1 * 4];
            stf4(zp, ai); stf4(zp + 512, af);
            stf4(zp + 1024, ao); stf4(zp + 1536, ag);
        }
        __syncthreads();                                   // barY
        if (isD0 && kg == 0 && d0act) {                    // dec0 combine
            const float* zp = &zs0[r * 4];
            float4 zi4 = add4(add4(ai, xi), ldf4(zp));
            float4 zf4 = add4(add4(af, xf), ldf4(zp + 1024));
            float4 zo4 = add4(add4(ao, xo), ldf4(zp + 2048));
            float4 zg4 = add4(add4(ag, xg), ldf4(zp + 3072));
            float4 h0q = gate4(zi4, zf4, zo4, zg4, bi, bfv, bo, bg, c0v);
            stf4(&hp0[ch0 * RS2 + 4 + t0f], h0q);
            if ((r & 7) == (s ? 0 : 7)) {                  // boundary col owner
                __hip_atomic_store((unsigned int*)&send0[(u & 1) * 32 + ch0],
                                   __float_as_uint(s ? h0q.x : h0q.w),
                                   __ATOMIC_RELAXED, __HIP_MEMORY_SCOPE_AGENT);
            }
        } else if (!isD0 && d1g == 0 && d1act) {           // dec1 combine
            const float* p0 = &zs1_3[0 * 2048 + rg1 * 4];
            const float* p1 = &zs1_3[1 * 2048 + rg1 * 4];
            const float* p2 = &zs1_3[2 * 2048 + rg1 * 4];
            float4 zi4 = add4(add4(ai, ldf4(p0)),        add4(ldf4(p1),        ldf4(p2)));
            float4 zf4 = add4(add4(af, ldf4(p0 + 512)),  add4(ldf4(p1 + 512),  ldf4(p2 + 512)));
            float4 zo4 = add4(add4(ao, ldf4(p0 + 1024)), add4(ldf4(p1 + 1024), ldf4(p2 + 1024)));
            float4 zg4 = add4(add4(ag, ldf4(p0 + 1536)), add4(ldf4(p1 + 1536), ldf4(p2 + 1536)));
            float4 h1q = gate4(zi4, zf4, zo4, zg4, bi, bfv, bo, bg, c1v);
            stf4(&hp1[ch1 * RS2 + 4 + t1f], h1q);
            if ((rg1 & 7) == (s ? 0 : 7)) {
                __hip_atomic_store((unsigned int*)&send1[(u & 1) * 16 + ch1],
                                   __float_as_uint(s ? h1q.x : h1q.w),
                                   __ATOMIC_RELAXED, __HIP_MEMORY_SCOPE_AGENT);
            }
        }
        __syncthreads();                                   // barZ (drains sends)
    }

    // tail fc(T_-1) on final chunk (hp1 holds h1(T_-1) after last phase)
    if (lastc && tid < 32) {
        float a = fcbv;
#pragma unroll
        for (int k2 = 0; k2 < 16; ++k2)
            a = fmaf(fcw[k2], hp1[k2 * RS2 + 4 + tid], a);
        out[(b * T_ + (T_ - 1)) * 64 + gofs + tid] = a;
    }
    // save state (chunk carry; safe vs peer: mutual per-phase waits bound drift)
    {
        int c8 = tid >> 5, f = tid & 31;
        h0sv[b * 2048 + c8 * 64 + gofs + f] = hp0[c8 * RS2 + 4 + f];
        if (tid < 512)
            h1sv[b * 1024 + (tid >> 5) * 64 + gofs + (tid & 31)] =
                hp1[(tid >> 5) * RS2 + 4 + (tid & 31)];
    }
    if (isD0 && kg == 0)
        stf4(&c0sv[b * 2048 + ch0 * 64 + gofs + t0f], c0v);
    if (!isD0 && d1g == 0)
        stf4(&c1sv[b * 1024 + ch1 * 64 + gofs + t1f], c1v);
}

// ---------------------------------------------------------------------------
// Fallback (ws too small for zx): fused x+h decoders.
// ---------------------------------------------------------------------------
__global__ __launch_bounds__(512, 1) void dec0_fb(
    const float* __restrict__ w, const float* __restrict__ bias,
    float* __restrict__ seq,
    const float* __restrict__ hin, const float* __restrict__ cin)
{
    __shared__ float wl[192 * 128];
    __shared__ float bs[128];
    __shared__ float xin[32 * RS];
    __shared__ float hp[32 * RS];

    const int tid = threadIdx.x;
    const int b = blockIdx.x;

    for (int idx = tid; idx < 192 * 128; idx += 512) {
        int k = idx >> 7, rr = idx & 127;
        int ch = rr >> 2, g = rr & 3;
        int ci = k / 3, d = k - ci * 3;
        wl[idx] = w[((g * 32 + ch) * 64 + ci) * 9 + d * 3 + 1];
    }
    if (tid < 128) bs[tid] = bias[tid];
    for (int i = tid; i < 32 * RS; i += 512) { xin[i] = 0.f; hp[i] = 0.f; }
    __syncthreads();
    {
        const float* hs = &hin[b * 2048 + tid * 4];
        float4 hv = ldf4(hs);
        int ci = tid >> 4, col = (tid & 15) * 4;
        stf4(&hp[ci * RS + 4 + col], hv);
    }
    const int ch = tid >> 4, f0 = (tid & 15) * 4;
    float4 cc = ldf4(&cin[b * 2048 + ch * 64 + f0]);
    const float bi = bs[ch], bf = bs[32 + ch], bo = bs[64 + ch], bg = bs[96 + ch];
    const float4 z4 = make_float4(0.f,0.f,0.f,0.f);

    float4 nx = ldf4(&seq[(size_t)b * 2048 + tid * 4]);

#pragma unroll 1
    for (int t = 0; t < T_; ++t) {
        {
            int ci = tid >> 4, col = (tid & 15) * 4;
            stf4(&xin[ci * RS + 4 + col], nx);
        }
        __syncthreads();
        if (t + 1 < T_)
            nx = ldf4(&seq[((size_t)(t + 1) * B_ + b) * 2048 + tid * 4]);
        float4 ai = z4, af = z4, ao = z4, ag = z4;
#pragma unroll 1
        for (int rr = 0; rr < 32; ++rr)
            rowacc4<128>(&xin[rr * RS + 4 + f0], wl + (rr * 3) * 128 + ch * 4, ai, af, ao, ag);
#pragma unroll 1
        for (int rr = 0; rr < 32; ++rr)
            rowacc4<128>(&hp[rr * RS + 4 + f0], wl + ((32 + rr) * 3) * 128 + ch * 4, ai, af, ao, ag);
        float4 hn = gate4(ai, af, ao, ag, bi, bf, bo, bg, cc);
        __syncthreads();
        stf4(&hp[ch * RS + 4 + f0], hn);
        stf4(&seq[((size_t)t * B_ + b) * 2048 + ch * 64 + f0], hn);
    }
}

__global__ __launch_bounds__(512, 1) void dec1_fb(
    const float* __restrict__ w, const float* __restrict__ bias,
    const float* __restrict__ seq,
    const float* __restrict__ hin, const float* __restrict__ cin,
    const float* __restrict__ fw, const float* __restrict__ fb,
    float* __restrict__ out)
{
    __shared__ float wl[144 * 64];
    __shared__ float bs[64];
    __shared__ float xin[32 * RS];
    __shared__ float hp[16 * RS];
    __shared__ float fcw[16];
    __shared__ float fcb;

    const int tid = threadIdx.x;
    const int b = blockIdx.x;

    for (int idx = tid; idx < 144 * 64; idx += 512) {
        int k = idx >> 6, rr = idx & 63;
        int ch = rr >> 2, g = rr & 3;
        int ci = k / 3, d = k - ci * 3;
        wl[idx] = w[((g * 16 + ch) * 48 + ci) * 9 + d * 3 + 1];
    }
    if (tid < 64) bs[tid] = bias[tid];
    if (tid < 16) fcw[tid] = fw[tid];
    if (tid == 16) fcb = fb[0];
    for (int i = tid; i < 32 * RS; i += 512) xin[i] = 0.f;
    for (int i = tid; i < 16 * RS; i += 512) hp[i] = 0.f;
    __syncthreads();
    {
        const float* hs = &hin[b * 1024 + tid * 2];
        float2 hv = *reinterpret_cast<const float2*>(hs);
        int ci = tid >> 5, col = (tid & 31) * 2;
        *reinterpret_cast<float2*>(&hp[ci * RS + 4 + col]) = hv;
    }
    const int ch = tid >> 5, f0 = (tid & 31) * 2;
    float2 cc = *reinterpret_cast<const float2*>(&cin[b * 1024 + ch * 64 + f0]);
    const float bi = bs[ch], bf = bs[16 + ch], bo = bs[32 + ch], bg = bs[48 + ch];
    const float2 z2 = make_float2(0.f,0.f);
    float4 nx = ldf4(&seq[(size_t)b * 2048 + tid * 4]);
    __syncthreads();

#pragma unroll 1
    for (int t = 0; t < T_; ++t) {
        {
            int ci = tid >> 4, col = (tid & 15) * 4;
            stf4(&xin[ci * RS + 4 + col], nx);
        }
        __syncthreads();
        if (t + 1 < T_)
            nx = ldf4(&seq[((size_t)(t + 1) * B_ + b) * 2048 + tid * 4]);

        float2 ai = z2, af = z2, ao = z2, ag = z2;
#pragma unroll 1
        for (int rr = 0; rr < 32; ++rr)
            rowacc2<64>(&xin[rr * RS + 4 + f0], wl + (rr * 3) * 64 + ch * 4, ai, af, ao, ag);
#pragma unroll 1
        for (int rr = 0; rr < 16; ++rr)
            rowacc2<64>(&hp[rr * RS + 4 + f0], wl + ((32 + rr) * 3) * 64 + ch * 4, ai, af, ao, ag);

        float2 hh;
        hh.x = gate1(ai.x + bi, af.x + bf, ao.x + bo, ag.x + bg, cc.x);
        hh.y = gate1(ai.y + bi, af.y + bf, ao.y + bo, ag.y + bg, cc.y);
        __syncthreads();
        *reinterpret_cast<float2*>(&hp[ch * RS + 4 + f0]) = hh;
        __syncthreads();

        if (tid < 64) {
            float a = fcb;
#pragma unroll
            for (int k2 = 0; k2 < 16; ++k2)
                a = fmaf(fcw[k2], hp[k2 * RS + 4 + tid], a);
            out[(b * T_ + t) * 64 + tid] = a;
        }
    }
}

// ---------------------------------------------------------------------------
extern "C" void kernel_launch(void* const* d_in, const int* in_sizes, int n_in,
                              void* d_out, int out_size, void* d_ws, size_t ws_size,
                              hipStream_t stream)
{
    (void)in_sizes; (void)n_in; (void)out_size;
    const float* x   = (const float*)d_in[0];
    const float* ew0 = (const float*)d_in[1];
    const float* eb0 = (const float*)d_in[2];
    const float* ew1 = (const float*)d_in[3];
    const float* eb1 = (const float*)d_in[4];
    const float* dw0 = (const float*)d_in[5];
    const float* db0 = (const float*)d_in[6];
    const float* dw1 = (const float*)d_in[7];
    const float* db1 = (const float*)d_in[8];
    const float* fw  = (const float*)d_in[9];
    const float* fb  = (const float*)d_in[10];
    float* out = (float*)d_out;

    float* ws  = (float*)d_ws;
    size_t off = 0;
    float* seq = ws + off; off += (size_t)T_ * B_ * 2048;
    float* h1f = ws + off; off += (size_t)B_ * 1024;
    float* c1f = ws + off; off += (size_t)B_ * 1024;
    float* h2f = ws + off; off += (size_t)B_ * 2048;
    float* c2f = ws + off; off += (size_t)B_ * 2048;
    float* hd0 = ws + off; off += (size_t)B_ * 2048;
    float* cd0 = ws + off; off += (size_t)B_ * 2048;
    float* hd1 = ws + off; off += (size_t)B_ * 1024;
    float* cd1 = ws + off; off += (size_t)B_ * 1024;
    float* comm = ws + off; off += 32768 + 16384 + 8192;   // enc | dec0 | dec1
    int*   flg  = (int*)(ws + off); off += 1024;           // enc[0..255] dec[256..511]
    float* zx  = ws + off;

    float* commD0 = comm + 32768;
    float* commD1 = comm + 32768 + 16384;

    size_t availf = (ws_size / 4 > off) ? (ws_size / 4 - off) : 0;
    int TC = 0;
    if      (availf >= (size_t)100 * B_ * 8192) TC = 100;
    else if (availf >= (size_t)50  * B_ * 8192) TC = 50;
    else if (availf >= (size_t)25  * B_ * 8192) TC = 25;
    else if (availf >= (size_t)10  * B_ * 8192) TC = 10;

    hipMemsetAsync(flg, 0, 512 * sizeof(int), stream);
    enc_kernel<<<256, 1024, 0, stream>>>(x, ew0, eb0, ew1, eb1, seq,
                                         h1f, c1f, h2f, c2f, comm, flg);

    if (TC > 0) {
        for (int t0 = 0; t0 < T_; t0 += TC) {
            int tn = (t0 + TC <= T_) ? TC : (T_ - t0);
            int lastc = (t0 + tn >= T_) ? 1 : 0;
            xconv0_kernel<<<tn * B_, 256, 0, stream>>>(seq, dw0, zx, t0);
            decg<<<256, 1024, 0, stream>>>(
                dw0, db0, dw1, db1, zx,
                t0 == 0 ? h2f : hd0, t0 == 0 ? c2f : cd0,
                t0 == 0 ? h1f : hd1, t0 == 0 ? c1f : cd1,
                hd0, cd0, hd1, cd1,
                fw, fb, out, commD0, commD1, flg + 256, t0, tn, lastc);
        }
    } else {
        dec0_fb<<<B_, 512, 0, stream>>>(dw0, db0, seq, h2f, c2f);
        dec1_fb<<<B_, 512, 0, stream>>>(dw1, db1, seq, h1f, c1f, fw, fb, out);
    }
}

// Round 12
// 1799.951 us; speedup vs baseline: 1.1165x; 1.1165x over previous
//
#include <hip/hip_runtime.h>
#include <math.h>

#define B_ 128
#define T_ 100
#define RS 72      // padded row stride (words) for full-width kernels
#define RS2 40     // f-split row stride: [0..2] zero, [3] halo-L, [4..35] own, [36] halo-R, [37..39] zero

// ---------------------------------------------------------------------------
// Fast transcendentals (~1e-6 rel err; threshold 1.27e-4)
// ---------------------------------------------------------------------------
__device__ __forceinline__ float frcp_(float x){ return __builtin_amdgcn_rcpf(x); }
__device__ __forceinline__ float fsig_(float x){ return frcp_(1.f + __expf(-x)); }
__device__ __forceinline__ float ftanh_(float x){ float e = __expf(2.f*x); return 1.f - 2.f*frcp_(e+1.f); }
__device__ __forceinline__ float gate1(float zi, float zf, float zo, float zg, float& c){
    float cc = fsig_(zf)*c + fsig_(zi)*ftanh_(zg);
    c = cc;
    return fsig_(zo)*ftanh_(cc);
}
__device__ __forceinline__ float4 ldf4(const float* p){ return *reinterpret_cast<const float4*>(p); }
__device__ __forceinline__ void stf4(float* p, float4 v){ *reinterpret_cast<float4*>(p) = v; }
__device__ __forceinline__ float2 ldf2(const float* p){ return *reinterpret_cast<const float2*>(p); }
__device__ __forceinline__ void stf2(float* p, float2 v){ *reinterpret_cast<float2*>(p) = v; }
__device__ __forceinline__ float4 add4(float4 a, float4 b){
    return make_float4(a.x+b.x, a.y+b.y, a.z+b.z, a.w+b.w);
}
__device__ __forceinline__ float4 gate4(float4 zi, float4 zf, float4 zo, float4 zg,
                                        float bi, float bf, float bo, float bg, float4& c){
    float4 h;
    h.x = gate1(zi.x+bi, zf.x+bf, zo.x+bo, zg.x+bg, c.x);
    h.y = gate1(zi.y+bi, zf.y+bf, zo.y+bo, zg.y+bg, c.y);
    h.z = gate1(zi.z+bi, zf.z+bf, zo.z+bo, zg.z+bg, c.z);
    h.w = gate1(zi.w+bi, zf.w+bf, zo.w+bo, zg.w+bg, c.w);
    return h;
}

__device__ __forceinline__ void fma4v(float w, float u0,float u1,float u2,float u3, float4& a){
    a.x = fmaf(w,u0,a.x); a.y = fmaf(w,u1,a.y);
    a.z = fmaf(w,u2,a.z); a.w = fmaf(w,u3,a.w);
}
__device__ __forceinline__ void fma2v(float w, float u0,float u1, float2& a){
    a.x = fmaf(w,u0,a.x); a.y = fmaf(w,u1,a.y);
}

// ---------------------------------------------------------------------------
// Row accumulators, weights from LDS.
// CURRENCY MODEL (r8/r9): below LDS-pipe saturation these kernels are
// LATENCY-bound -> waves/CU is the lever (enc 838->781, decg similar at
// 8->16 waves). r11: group-rebalance is NULL (barrier/LDS-pipe floor, not
// max-group FMA). LDS LAYOUT RULE (r7): partial buffers lane-contiguous.
// Do NOT hoist weights to VGPRs (r2: spills).
// ---------------------------------------------------------------------------
template<int ROWS>
__device__ __forceinline__ void rowacc4(const float* __restrict__ rowp,
                                        const float* __restrict__ wk,
                                        float4& ai, float4& af, float4& ao, float4& ag)
{
    float  m = rowp[-1];
    float4 a = ldf4(rowp);
    float  p = rowp[4];
    float4 wa = ldf4(wk);
    float4 wb = ldf4(wk + ROWS);
    float4 wc = ldf4(wk + 2*ROWS);
    fma4v(wa.x, m,a.x,a.y,a.z, ai);  fma4v(wa.y, m,a.x,a.y,a.z, af);
    fma4v(wa.z, m,a.x,a.y,a.z, ao);  fma4v(wa.w, m,a.x,a.y,a.z, ag);
    fma4v(wb.x, a.x,a.y,a.z,a.w, ai); fma4v(wb.y, a.x,a.y,a.z,a.w, af);
    fma4v(wb.z, a.x,a.y,a.z,a.w, ao); fma4v(wb.w, a.x,a.y,a.z,a.w, ag);
    fma4v(wc.x, a.y,a.z,a.w,p, ai);  fma4v(wc.y, a.y,a.z,a.w,p, af);
    fma4v(wc.z, a.y,a.z,a.w,p, ao);  fma4v(wc.w, a.y,a.z,a.w,p, ag);
}
template<int ROWS>
__device__ __forceinline__ void rowacc2(const float* __restrict__ rowp,
                                        const float* __restrict__ wk,
                                        float2& ai, float2& af, float2& ao, float2& ag)
{
    float  m = rowp[-1];
    float2 a = *reinterpret_cast<const float2*>(rowp);
    float  p = rowp[2];
    float4 wa = ldf4(wk);
    float4 wb = ldf4(wk + ROWS);
    float4 wc = ldf4(wk + 2*ROWS);
    fma2v(wa.x, m,a.x, ai); fma2v(wa.y, m,a.x, af);
    fma2v(wa.z, m,a.x, ao); fma2v(wa.w, m,a.x, ag);
    fma2v(wb.x, a.x,a.y, ai); fma2v(wb.y, a.x,a.y, af);
    fma2v(wb.z, a.x,a.y, ao); fma2v(wb.w, a.x,a.y, ag);
    fma2v(wc.x, a.y,p, ai); fma2v(wc.y, a.y,p, af);
    fma2v(wc.z, a.y,p, ao); fma2v(wc.w, a.y,p, ag);
}
template<int ROWS>
__device__ __forceinline__ void rowacc8(const float* __restrict__ rowp,
                                        const float* __restrict__ wk,
                                        float4& i0, float4& i1, float4& f0v, float4& f1v,
                                        float4& o0, float4& o1, float4& g0, float4& g1)
{
    float  m = rowp[-1];
    float4 a = ldf4(rowp);
    float4 b = ldf4(rowp + 4);
    float  p = rowp[8];
    float4 wa = ldf4(wk);
    float4 wb = ldf4(wk + ROWS);
    float4 wc = ldf4(wk + 2*ROWS);
    fma4v(wa.x, m,a.x,a.y,a.z, i0);   fma4v(wa.x, a.w,b.x,b.y,b.z, i1);
    fma4v(wa.y, m,a.x,a.y,a.z, f0v);  fma4v(wa.y, a.w,b.x,b.y,b.z, f1v);
    fma4v(wa.z, m,a.x,a.y,a.z, o0);   fma4v(wa.z, a.w,b.x,b.y,b.z, o1);
    fma4v(wa.w, m,a.x,a.y,a.z, g0);   fma4v(wa.w, a.w,b.x,b.y,b.z, g1);
    fma4v(wb.x, a.x,a.y,a.z,a.w, i0); fma4v(wb.x, b.x,b.y,b.z,b.w, i1);
    fma4v(wb.y, a.x,a.y,a.z,a.w, f0v);fma4v(wb.y, b.x,b.y,b.z,b.w, f1v);
    fma4v(wb.z, a.x,a.y,a.z,a.w, o0); fma4v(wb.z, b.x,b.y,b.z,b.w, o1);
    fma4v(wb.w, a.x,a.y,a.z,a.w, g0); fma4v(wb.w, b.x,b.y,b.z,b.w, g1);
    fma4v(wc.x, a.y,a.z,a.w,b.x, i0); fma4v(wc.x, b.y,b.z,b.w,p, i1);
    fma4v(wc.y, a.y,a.z,a.w,b.x, f0v);fma4v(wc.y, b.y,b.z,b.w,p, f1v);
    fma4v(wc.z, a.y,a.z,a.w,b.x, o0); fma4v(wc.z, b.y,b.z,b.w,p, o1);
    fma4v(wc.w, a.y,a.z,a.w,b.x, g0); fma4v(wc.w, b.y,b.z,b.w,p, g1);
}

// ---------------------------------------------------------------------------
// Encoder, f-split block pairs, 1024 threads (round-10 exact, 768 us,
// occupancy 47%). 4-way L1 row split 12/12/12/12 FT=4, lane-contiguous
// zsB3; L0 on g2/g3; x staging on g1. (r11 rebalance reverted: null.)
// ---------------------------------------------------------------------------
__global__ __launch_bounds__(1024, 4) void enc_kernel(
    const float* __restrict__ x,
    const float* __restrict__ w0, const float* __restrict__ b0,
    const float* __restrict__ w1, const float* __restrict__ b1,
    float* __restrict__ seq,
    float* __restrict__ h1f, float* __restrict__ c1f,
    float* __restrict__ h2f, float* __restrict__ c2f,
    float* __restrict__ comm, int* __restrict__ flags)
{
    __shared__ float wl0[51 * 64];     // k=(ci*3+d), ci<17, col=ch*4+g (CH=16)
    __shared__ float wl1[144 * 128];   // ci<48 (0..15 = h0, 16..47 = h1)
    __shared__ float bs0[64];
    __shared__ float bs1[128];
    __shared__ float hbuf[50 * RS2];   // rows 0,1 = x dbuf; 2..17 h0; 18..49 h1
    __shared__ float zsA[2048];        // L0 partial (g3): q*512 + 2*r
    __shared__ float zsB3[3 * 4096];   // L1 partials (g1..3): set*4096 + q*1024 + 4*r

    const int tid = threadIdx.x;
    const int b = blockIdx.x & 127;
    const int s = blockIdx.x >> 7;
    const int gofs = s << 5;
    const int g  = tid >> 8;            // row-group 0..3
    const int r  = tid & 255;
    const int chB = r >> 3, f0B = (r & 7) * 4;    // L1: 32ch x 8 tiles, FT=4
    const int chA = r >> 4, f0A = (r & 15) * 2;   // L0: 16ch x 16 tiles, FT=2
    const int haloSlot = s ? 3 : 36;
    const int myId = (b << 1) | s;
    const int peerId = myId ^ 1;
    float* mySend = &comm[(size_t)myId * 128];         // [par][64]: 0..31 h1, 32..47 h0
    const float* peerBuf = &comm[(size_t)peerId * 128];

    for (int idx = tid; idx < 51 * 64; idx += 1024) {
        int k = idx >> 6, rr = idx & 63;
        int ch = rr >> 2, gg = rr & 3;
        int ci = k / 3, d = k - ci * 3;
        wl0[idx] = w0[((gg * 16 + ch) * 17 + ci) * 9 + d * 3 + 1];
    }
    for (int idx = tid; idx < 144 * 128; idx += 1024) {
        int k = idx >> 7, rr = idx & 127;
        int ch = rr >> 2, gg = rr & 3;
        int ci = k / 3, d = k - ci * 3;
        wl1[idx] = w1[((gg * 32 + ch) * 48 + ci) * 9 + d * 3 + 1];
    }
    if (tid < 64) bs0[tid] = b0[tid];
    if (tid < 128) bs1[tid] = b1[tid];
    for (int i = tid; i < 50 * RS2; i += 1024) hbuf[i] = 0.f;
    __syncthreads();

    const int xl = tid - 256;           // g1 threads 256-289 stage x (34 cols)
    if (xl >= 0 && xl < 34) {
        const int gc = gofs - 1 + xl;
        const bool v = (gc >= 0) && (gc < 64);
        hbuf[0 * RS2 + 3 + xl] = v ? x[(b * T_ + 0) * 64 + gc] : 0.f;
        hbuf[1 * RS2 + 3 + xl] = v ? x[(b * T_ + 1) * 64 + gc] : 0.f;
    }
    const float biA = bs0[chA], bfA = bs0[16+chA], boA = bs0[32+chA], bgA = bs0[48+chA];
    const float biB = bs1[chB], bfB = bs1[32+chB], boB = bs1[64+chB], bgB = bs1[96+chB];
    __syncthreads();

    const float4 z4 = make_float4(0.f, 0.f, 0.f, 0.f);
    const float2 z2 = make_float2(0.f, 0.f);
    float2 c0q = z2;                    // L0 cell (g2, 2 cols)
    float4 c1a = z4;                    // L1 cell (g0, 4 cols)

    // ---- prologue: L0(0) from x(0); h0 rows zero so g3 partial is zero ----
    if (g == 2) {
        float2 ai = z2, af = z2, ao = z2, ag = z2;
        rowacc2<64>(&hbuf[0 * RS2 + 4 + f0A], &wl0[chA * 4], ai, af, ao, ag);
        float2 hq;
        hq.x = gate1(ai.x + biA, af.x + bfA, ao.x + boA, ag.x + bgA, c0q.x);
        hq.y = gate1(ai.y + biA, af.y + bfA, ao.y + boA, ag.y + bgA, c0q.y);
        *reinterpret_cast<float2*>(&hbuf[(2 + chA) * RS2 + 4 + f0A]) = hq;
        if ((r & 15) == (s ? 0 : 15)) {            // boundary column owner
            const float v = s ? hq.x : hq.y;
            __hip_atomic_store((unsigned int*)&mySend[1 * 64 + 32 + chA],
                               __float_as_uint(v),
                               __ATOMIC_RELAXED, __HIP_MEMORY_SCOPE_AGENT);
        }
    }
    __syncthreads();   // drains vmcnt -> prologue payload globally visible

#pragma unroll 1
    for (int t = 0; t < T_; ++t) {
        // publish exchange n = t+1 (payload stored before the last barrier)
        if (tid == 0)
            __hip_atomic_store(&flags[myId], t + 1,
                               __ATOMIC_RELAXED, __HIP_MEMORY_SCOPE_AGENT);
        // import partner halo column(s): h1(t-1) [tid<32], h0(t) [tid 32..47]
        if (tid < 48 && (t > 0 || tid >= 32)) {
            while (__hip_atomic_load(&flags[peerId],
                                     __ATOMIC_ACQUIRE, __HIP_MEMORY_SCOPE_AGENT) < t + 1)
                __builtin_amdgcn_s_sleep(2);
            const int par = (t + 1) & 1;
            const unsigned int uv =
                __hip_atomic_load((const unsigned int*)&peerBuf[par * 64 + tid],
                                  __ATOMIC_RELAXED, __HIP_MEMORY_SCOPE_AGENT);
            const float v = __uint_as_float(uv);
            if (tid < 32) hbuf[(18 + tid) * RS2 + haloSlot] = v;
            else          hbuf[(2 + (tid - 32)) * RS2 + haloSlot] = v;
        }
        __syncthreads();                                   // bar0

        const bool doL0 = (t + 1 < T_);
        // ================= P1: accumulate =================
        float4 I = z4, F = z4, O = z4, G = z4;             // L1(t), 4 cols, 12 rows
#pragma unroll 1
        for (int j = 0; j < 12; ++j) {
            const int ci = 12 * g + j;
            rowacc4<128>(&hbuf[(2 + ci) * RS2 + 4 + f0B],
                         &wl1[(ci * 3) * 128 + chB * 4], I, F, O, G);
        }
        float2 ai = z2, af = z2, ao = z2, ag = z2;         // L0(t+1), 2 cols
        if (doL0) {
            if (g == 2) {
                rowacc2<64>(&hbuf[((t + 1) & 1) * RS2 + 4 + f0A], &wl0[chA * 4],
                            ai, af, ao, ag);
#pragma unroll 1
                for (int j = 0; j < 8; ++j)
                    rowacc2<64>(&hbuf[(2 + j) * RS2 + 4 + f0A],
                                &wl0[((1 + j) * 3) * 64 + chA * 4], ai, af, ao, ag);
            } else if (g == 3) {
#pragma unroll 1
                for (int j = 8; j < 16; ++j)
                    rowacc2<64>(&hbuf[(2 + j) * RS2 + 4 + f0A],
                                &wl0[((1 + j) * 3) * 64 + chA * 4], ai, af, ao, ag);
            }
        }
        if (g != 0) {                   // L1 partial -> zsB3 (lane-contiguous 4r)
            float* zp = &zsB3[(g - 1) * 4096 + r * 4];
            stf4(zp, I); stf4(zp + 1024, F); stf4(zp + 2048, O); stf4(zp + 3072, G);
        }
        if (g == 3 && doL0) {           // L0 partial -> zsA (lane-contiguous 2r)
            float* zp = &zsA[r * 2];
            stf2(zp, ai); stf2(zp + 512, af); stf2(zp + 1024, ao); stf2(zp + 1536, ag);
        }
        if (xl >= 0 && xl < 34 && t + 2 < T_) {            // g1 stages x(t+2)
            const int gc = gofs - 1 + xl;
            hbuf[(t & 1) * RS2 + 3 + xl] =
                (gc >= 0 && gc < 64) ? x[(b * T_ + t + 2) * 64 + gc] : 0.f;
        }
        __syncthreads();                                   // barY
        // ================= P2: combine + gates + send =================
        if (g == 0) {                                      // L1 combine (FT=4)
            const float* p0 = &zsB3[0 * 4096 + r * 4];
            const float* p1 = &zsB3[1 * 4096 + r * 4];
            const float* p2 = &zsB3[2 * 4096 + r * 4];
            float4 zi = add4(add4(I, ldf4(p0)),        add4(ldf4(p1),        ldf4(p2)));
            float4 zf = add4(add4(F, ldf4(p0 + 1024)), add4(ldf4(p1 + 1024), ldf4(p2 + 1024)));
            float4 zo = add4(add4(O, ldf4(p0 + 2048)), add4(ldf4(p1 + 2048), ldf4(p2 + 2048)));
            float4 zg = add4(add4(G, ldf4(p0 + 3072)), add4(ldf4(p1 + 3072), ldf4(p2 + 3072)));
            float4 hq = gate4(zi, zf, zo, zg, biB, bfB, boB, bgB, c1a);
            stf4(&hbuf[(18 + chB) * RS2 + 4 + f0B], hq);
            stf4(&seq[((size_t)t * B_ + b) * 2048 + chB * 64 + gofs + f0B], hq);
            if (doL0 && (r & 7) == (s ? 0 : 7)) {          // h1 boundary col
                const float v = s ? hq.x : hq.w;
                __hip_atomic_store((unsigned int*)&mySend[(t & 1) * 64 + chB],
                                   __float_as_uint(v),
                                   __ATOMIC_RELAXED, __HIP_MEMORY_SCOPE_AGENT);
            }
        }
        if (g == 2 && doL0) {                              // L0 combine (FT=2)
            float2 pzi = ldf2(&zsA[r * 2]);
            float2 pzf = ldf2(&zsA[512 + r * 2]);
            float2 pzo = ldf2(&zsA[1024 + r * 2]);
            float2 pzg = ldf2(&zsA[1536 + r * 2]);
            float2 hq2;
            hq2.x = gate1(ai.x+pzi.x+biA, af.x+pzf.x+bfA, ao.x+pzo.x+boA, ag.x+pzg.x+bgA, c0q.x);
            hq2.y = gate1(ai.y+pzi.y+biA, af.y+pzf.y+bfA, ao.y+pzo.y+boA, ag.y+pzg.y+bgA, c0q.y);
            *reinterpret_cast<float2*>(&hbuf[(2 + chA) * RS2 + 4 + f0A]) = hq2;
            if ((r & 15) == (s ? 0 : 15)) {
                const float v = s ? hq2.x : hq2.y;
                __hip_atomic_store((unsigned int*)&mySend[(t & 1) * 64 + 32 + chA],
                                   __float_as_uint(v),
                                   __ATOMIC_RELAXED, __HIP_MEMORY_SCOPE_AGENT);
            }
        }
        __syncthreads();                                   // barZ (drains sends)
    }

    // final states: L0 on g2 threads (FT=2), L1 on g0 threads (FT=4)
    if (g == 2) {
        *reinterpret_cast<float2*>(&h1f[(b * 16 + chA) * 64 + gofs + f0A]) =
            *reinterpret_cast<const float2*>(&hbuf[(2 + chA) * RS2 + 4 + f0A]);
        *reinterpret_cast<float2*>(&c1f[(b * 16 + chA) * 64 + gofs + f0A]) = c0q;
    }
    if (g == 0) {
        stf4(&h2f[b * 2048 + chB * 64 + gofs + f0B],
             ldf4(&hbuf[(18 + chB) * RS2 + 4 + f0B]));
        stf4(&c2f[b * 2048 + chB * 64 + gofs + f0B], c1a);
    }
}

// ---------------------------------------------------------------------------
// xconv0: parallel x-part pre-activations for dec0. Round-12: one block
// handles TB=4 timesteps of the same b, loading the 48 KB weight tile ONCE
// (was once per (t,b): 12800 x 48 KB). Loop: stage xt(t) | bar | compute +
// write zx | bar. zx layout/indexing unchanged (tl = chunk-local step).
// ---------------------------------------------------------------------------
#define XTB 4
__global__ __launch_bounds__(256, 2) void xconv0_kernel(
    const float* __restrict__ seqIn, const float* __restrict__ w,
    float* __restrict__ zx, int t0, int tn)
{
    __shared__ float wl[96 * 128];
    __shared__ float xt[32 * RS];

    const int tid = threadIdx.x;
    const int nb = blockIdx.x / B_;          // chunk index
    const int b  = blockIdx.x - nb * B_;
    const int tl0 = nb * XTB;
    const int tlEnd = (tl0 + XTB < tn) ? (tl0 + XTB) : tn;

    for (int idx = tid; idx < 96 * 128; idx += 256) {
        int k = idx >> 7, rr = idx & 127;
        int ch = rr >> 2, g = rr & 3;
        int ci = k / 3, d = k - ci * 3;
        wl[idx] = w[((g * 32 + ch) * 64 + ci) * 9 + d * 3 + 1];
    }
    {   // zero pad columns once (stage loop only writes cols 4..67)
        int rr = tid >> 3, j = tid & 7;
        xt[rr * RS + (j < 4 ? j : 64 + j)] = 0.f;
    }

    const int ch = tid >> 3, f0 = (tid & 7) * 8;
    const int sci = tid >> 3, scol = (tid & 7) * 8;
    const float4 z4 = make_float4(0.f,0.f,0.f,0.f);

#pragma unroll 1
    for (int tl = tl0; tl < tlEnd; ++tl) {
        const int t = t0 + tl;
        {   // stage xt(t)
            const float* sp = &seqIn[((size_t)t * B_ + b) * 2048 + tid * 8];
            float4 v0 = ldf4(sp);
            float4 v1 = ldf4(sp + 4);
            stf4(&xt[sci * RS + 4 + scol], v0);
            stf4(&xt[sci * RS + 4 + scol + 4], v1);
        }
        __syncthreads();                       // xt ready (and wl on first iter)

        float4 i0=z4,i1=z4,f0v=z4,f1v=z4,o0=z4,o1=z4,g0=z4,g1=z4;
#pragma unroll 1
        for (int rr = 0; rr < 32; ++rr)
            rowacc8<128>(&xt[rr * RS + 4 + f0], wl + (rr * 3) * 128 + ch * 4,
                         i0, i1, f0v, f1v, o0, o1, g0, g1);

        float* zp = &zx[(((size_t)tl * B_ + b) * 4) * 2048 + ch * 64 + f0];
        stf4(zp, i0);            stf4(zp + 4, i1);
        stf4(zp + 2048, f0v);    stf4(zp + 2048 + 4, f1v);
        stf4(zp + 4096, o0);     stf4(zp + 4096 + 4, o1);
        stf4(zp + 6144, g0);     stf4(zp + 6144 + 4, g1);
        __syncthreads();                       // compute done before restage
    }
}

// ---------------------------------------------------------------------------
// decg: fused skewed decoder, f-split block pairs, 1024 threads (round-10).
// Phase u: dec0(u) AND dec1(u-1). dec0: tid 0-511, kg=2 x 256 lanes FT=4,
// 16 rows each, zs0 lane-contiguous. dec1: tid 512-1023, 4 groups x 128
// lanes FT=4, 12 rows each, zs1_3 lane-contiguous. UNCHANGED this round.
// ---------------------------------------------------------------------------
__global__ __launch_bounds__(1024, 4) void decg(
    const float* __restrict__ w0, const float* __restrict__ b0,
    const float* __restrict__ w1, const float* __restrict__ b1,
    const float* __restrict__ zx,
    const float* __restrict__ h0in, const float* __restrict__ c0in,
    const float* __restrict__ h1in, const float* __restrict__ c1in,
    float* __restrict__ h0sv, float* __restrict__ c0sv,
    float* __restrict__ h1sv, float* __restrict__ c1sv,
    const float* __restrict__ fw, const float* __restrict__ fb,
    float* __restrict__ out,
    float* __restrict__ comm0, float* __restrict__ comm1,
    int* __restrict__ flg, int t0, int tn, int lastc)
{
    __shared__ float wl0[96 * 128];    // dec0 h-rows only (w row 32+ci)
    __shared__ float wl1[144 * 64];    // dec1 x-rows (0..31) + h-rows (32..47)
    __shared__ float hp0[32 * RS2];
    __shared__ float hp1[16 * RS2];
    __shared__ float zs0[4096];        // dec0 partials (kg1): q*1024 + 4*r
    __shared__ float zs1_3[3 * 2048];  // dec1 partials: set*2048 + q*512 + 4*rg1
    __shared__ float bs0[128];
    __shared__ float bs1[64];
    __shared__ float fcw[16];
    __shared__ float fcb_s;

    const int tid = threadIdx.x;
    const int b = blockIdx.x & 127;
    const int s = blockIdx.x >> 7;
    const int gofs = s << 5;
    const int haloSlot = s ? 3 : 36;
    const int bcol = s ? 31 : 32;
    const int myId = (b << 1) | s, peerId = myId ^ 1;
    float* send0 = &comm0[(size_t)myId * 64];          // [par][32ch]
    const float* peer0 = &comm0[(size_t)peerId * 64];
    float* send1 = &comm1[(size_t)myId * 32];          // [par][16ch]
    const float* peer1 = &comm1[(size_t)peerId * 32];

    const bool isD0 = (tid < 512);
    const int sub = tid & 511;
    const int kg = sub >> 8;                           // dec0 half 0/1
    const int r = sub & 255;
    const int ch0 = r >> 3, t0f = (r & 7) * 4;        // dec0: 32ch x 8 tiles FT=4
    const int d1g = sub >> 7;                          // dec1 group 0..3
    const int rg1 = sub & 127;
    const int ch1 = rg1 >> 3, t1f = (rg1 & 7) * 4;    // dec1: 16ch x 8 tiles FT=4

    for (int idx = tid; idx < 96 * 128; idx += 1024) {
        int k = idx >> 7, rr = idx & 127;
        int c8 = rr >> 2, g = rr & 3;
        int ci = k / 3, d = k - ci * 3;
        wl0[idx] = w0[((g * 32 + c8) * 64 + 32 + ci) * 9 + d * 3 + 1];
    }
    for (int idx = tid; idx < 144 * 64; idx += 1024) {
        int k = idx >> 6, rr = idx & 63;
        int c8 = rr >> 2, g = rr & 3;
        int ci = k / 3, d = k - ci * 3;
        wl1[idx] = w1[((g * 16 + c8) * 48 + ci) * 9 + d * 3 + 1];
    }
    if (tid < 128) bs0[tid] = b0[tid];
    if (tid < 64) bs1[tid] = b1[tid];
    if (tid < 16) fcw[tid] = fw[tid];
    if (tid == 16) fcb_s = fb[0];
    for (int i = tid; i < 32 * RS2; i += 1024) hp0[i] = 0.f;
    for (int i = tid; i < 16 * RS2; i += 1024) hp1[i] = 0.f;
    __syncthreads();

    // restore states (own cols + boundary halo from peer's saved full-width h)
    {
        int c8 = tid >> 5, f = tid & 31;
        hp0[c8 * RS2 + 4 + f] = h0in[b * 2048 + c8 * 64 + gofs + f];
        if (tid < 512)
            hp1[(tid >> 5) * RS2 + 4 + (tid & 31)] =
                h1in[b * 1024 + (tid >> 5) * 64 + gofs + (tid & 31)];
    }
    if (tid < 32) hp0[tid * RS2 + haloSlot] = h0in[b * 2048 + tid * 64 + bcol];
    if (tid >= 64 && tid < 80)
        hp1[(tid - 64) * RS2 + haloSlot] = h1in[b * 1024 + (tid - 64) * 64 + bcol];

    const float4 z4 = make_float4(0.f, 0.f, 0.f, 0.f);
    float4 c0v = z4;                    // dec0 cell (kg0 & isD0, 4 cols)
    float4 c1v = z4;                    // dec1 cell (d1g==0)
    float bi, bfv, bo, bg;
    if (isD0) { bi = bs0[ch0]; bfv = bs0[32+ch0]; bo = bs0[64+ch0]; bg = bs0[96+ch0]; }
    else      { bi = bs1[ch1]; bfv = bs1[16+ch1]; bo = bs1[32+ch1]; bg = bs1[48+ch1]; }
    if (isD0 && kg == 0)
        c0v = ldf4(&c0in[b * 2048 + ch0 * 64 + gofs + t0f]);
    if (!isD0 && d1g == 0)
        c1v = ldf4(&c1in[b * 1024 + ch1 * 64 + gofs + t1f]);
    const float fcbv = fcb_s;

#pragma unroll 1
    for (int u = t0; u < t0 + tn + lastc; ++u) {
        // publish: my P2(u-1) payloads are visible (barZ drained vmcnt)
        if (tid == 0)
            __hip_atomic_store(&flg[myId], u,
                               __ATOMIC_RELAXED, __HIP_MEMORY_SCOPE_AGENT);
        if (u > t0) {
            const int par = (u - 1) & 1;
            if (tid < 32) {                         // h0(u-1) halo
                while (__hip_atomic_load(&flg[peerId],
                                         __ATOMIC_ACQUIRE, __HIP_MEMORY_SCOPE_AGENT) < u)
                    __builtin_amdgcn_s_sleep(2);
                hp0[tid * RS2 + haloSlot] = __uint_as_float(
                    __hip_atomic_load((const unsigned int*)&peer0[par * 32 + tid],
                                      __ATOMIC_RELAXED, __HIP_MEMORY_SCOPE_AGENT));
            } else if (tid >= 64 && tid < 80 && u >= 2) {   // h1(u-2) halo
                while (__hip_atomic_load(&flg[peerId],
                                         __ATOMIC_ACQUIRE, __HIP_MEMORY_SCOPE_AGENT) < u)
                    __builtin_amdgcn_s_sleep(2);
                hp1[(tid - 64) * RS2 + haloSlot] = __uint_as_float(
                    __hip_atomic_load((const unsigned int*)&peer1[par * 16 + (tid - 64)],
                                      __ATOMIC_RELAXED, __HIP_MEMORY_SCOPE_AGENT));
            }
        }
        __syncthreads();                                   // bar0

        const bool d0act = (u - t0 < tn);                  // u < t0+tn (=> u < T_)
        const bool d1act = (u >= 1);
        float4 ai = z4, af = z4, ao = z4, ag = z4;         // shared acc (FT=4)
        float4 xi = z4, xf = z4, xo = z4, xg = z4;         // zx prefetch (dec0 kg0)

        if (isD0) {
            if (d0act) {
                if (kg == 0) {
                    const float* zp = &zx[(((size_t)(u - t0) * B_ + b) * 4) * 2048
                                          + ch0 * 64 + gofs + t0f];
                    xi = ldf4(zp);
                    xf = ldf4(zp + 2048);
                    xo = ldf4(zp + 4096);
                    xg = ldf4(zp + 6144);
                }
#pragma unroll 1
                for (int j = 0; j < 16; ++j) {
                    const int ci = kg * 16 + j;
                    rowacc4<128>(&hp0[ci * RS2 + 4 + t0f], &wl0[(ci * 3) * 128 + ch0 * 4],
                                 ai, af, ao, ag);
                }
            }
            if (kg == 1 && r < 32 && u >= 2) {             // fc(u-2): hp1 = h1(u-2)
                float a = fcbv;
#pragma unroll
                for (int k2 = 0; k2 < 16; ++k2)
                    a = fmaf(fcw[k2], hp1[k2 * RS2 + 4 + r], a);
                out[(b * T_ + (u - 2)) * 64 + gofs + r] = a;
            }
        } else if (d1act) {
            const int rlo = 12 * d1g, rhi = rlo + 12;
            const int xhi = rhi < 32 ? rhi : 32;
            const int hlo = rlo > 32 ? rlo : 32;
#pragma unroll 1
            for (int rr = rlo; rr < xhi; ++rr)             // x rows (h0(u-1))
                rowacc4<64>(&hp0[rr * RS2 + 4 + t1f], &wl1[(rr * 3) * 64 + ch1 * 4],
                            ai, af, ao, ag);
#pragma unroll 1
            for (int rr = hlo; rr < rhi; ++rr)             // h rows (h1(u-2))
                rowacc4<64>(&hp1[(rr - 32) * RS2 + 4 + t1f], &wl1[(rr * 3) * 64 + ch1 * 4],
                            ai, af, ao, ag);
        }
        if (isD0) {
            if (kg == 1 && d0act) {                        // lane-contiguous r*4
                float* zp = &zs0[r * 4];
                stf4(zp, ai); stf4(zp + 1024, af);
                stf4(zp + 2048, ao); stf4(zp + 3072, ag);
            }
        } else if (d1g != 0 && d1act) {                    // lane-contiguous rg1*4
            float* zp = &zs1_3[(d1g - 1) * 2048 + rg1 * 4];
            stf4(zp, ai); stf4(zp + 512, af);
            stf4(zp + 1024, ao); stf4(zp + 1536, ag);
        }
        __syncthreads();                                   // barY
        if (isD0 && kg == 0 && d0act) {                    // dec0 combine
            const float* zp = &zs0[r * 4];
            float4 zi4 = add4(add4(ai, xi), ldf4(zp));
            float4 zf4 = add4(add4(af, xf), ldf4(zp + 1024));
            float4 zo4 = add4(add4(ao, xo), ldf4(zp + 2048));
            float4 zg4 = add4(add4(ag, xg), ldf4(zp + 3072));
            float4 h0q = gate4(zi4, zf4, zo4, zg4, bi, bfv, bo, bg, c0v);
            stf4(&hp0[ch0 * RS2 + 4 + t0f], h0q);
            if ((r & 7) == (s ? 0 : 7)) {                  // boundary col owner
                __hip_atomic_store((unsigned int*)&send0[(u & 1) * 32 + ch0],
                                   __float_as_uint(s ? h0q.x : h0q.w),
                                   __ATOMIC_RELAXED, __HIP_MEMORY_SCOPE_AGENT);
            }
        } else if (!isD0 && d1g == 0 && d1act) {           // dec1 combine
            const float* p0 = &zs1_3[0 * 2048 + rg1 * 4];
            const float* p1 = &zs1_3[1 * 2048 + rg1 * 4];
            const float* p2 = &zs1_3[2 * 2048 + rg1 * 4];
            float4 zi4 = add4(add4(ai, ldf4(p0)),        add4(ldf4(p1),        ldf4(p2)));
            float4 zf4 = add4(add4(af, ldf4(p0 + 512)),  add4(ldf4(p1 + 512),  ldf4(p2 + 512)));
            float4 zo4 = add4(add4(ao, ldf4(p0 + 1024)), add4(ldf4(p1 + 1024), ldf4(p2 + 1024)));
            float4 zg4 = add4(add4(ag, ldf4(p0 + 1536)), add4(ldf4(p1 + 1536), ldf4(p2 + 1536)));
            float4 h1q = gate4(zi4, zf4, zo4, zg4, bi, bfv, bo, bg, c1v);
            stf4(&hp1[ch1 * RS2 + 4 + t1f], h1q);
            if ((rg1 & 7) == (s ? 0 : 7)) {
                __hip_atomic_store((unsigned int*)&send1[(u & 1) * 16 + ch1],
                                   __float_as_uint(s ? h1q.x : h1q.w),
                                   __ATOMIC_RELAXED, __HIP_MEMORY_SCOPE_AGENT);
            }
        }
        __syncthreads();                                   // barZ (drains sends)
    }

    // tail fc(T_-1) on final chunk (hp1 holds h1(T_-1) after last phase)
    if (lastc && tid < 32) {
        float a = fcbv;
#pragma unroll
        for (int k2 = 0; k2 < 16; ++k2)
            a = fmaf(fcw[k2], hp1[k2 * RS2 + 4 + tid], a);
        out[(b * T_ + (T_ - 1)) * 64 + gofs + tid] = a;
    }
    // save state (chunk carry; safe vs peer: mutual per-phase waits bound drift)
    {
        int c8 = tid >> 5, f = tid & 31;
        h0sv[b * 2048 + c8 * 64 + gofs + f] = hp0[c8 * RS2 + 4 + f];
        if (tid < 512)
            h1sv[b * 1024 + (tid >> 5) * 64 + gofs + (tid & 31)] =
                hp1[(tid >> 5) * RS2 + 4 + (tid & 31)];
    }
    if (isD0 && kg == 0)
        stf4(&c0sv[b * 2048 + ch0 * 64 + gofs + t0f], c0v);
    if (!isD0 && d1g == 0)
        stf4(&c1sv[b * 1024 + ch1 * 64 + gofs + t1f], c1v);
}

// ---------------------------------------------------------------------------
// Fallback (ws too small for zx): fused x+h decoders.
// ---------------------------------------------------------------------------
__global__ __launch_bounds__(512, 1) void dec0_fb(
    const float* __restrict__ w, const float* __restrict__ bias,
    float* __restrict__ seq,
    const float* __restrict__ hin, const float* __restrict__ cin)
{
    __shared__ float wl[192 * 128];
    __shared__ float bs[128];
    __shared__ float xin[32 * RS];
    __shared__ float hp[32 * RS];

    const int tid = threadIdx.x;
    const int b = blockIdx.x;

    for (int idx = tid; idx < 192 * 128; idx += 512) {
        int k = idx >> 7, rr = idx & 127;
        int ch = rr >> 2, g = rr & 3;
        int ci = k / 3, d = k - ci * 3;
        wl[idx] = w[((g * 32 + ch) * 64 + ci) * 9 + d * 3 + 1];
    }
    if (tid < 128) bs[tid] = bias[tid];
    for (int i = tid; i < 32 * RS; i += 512) { xin[i] = 0.f; hp[i] = 0.f; }
    __syncthreads();
    {
        const float* hs = &hin[b * 2048 + tid * 4];
        float4 hv = ldf4(hs);
        int ci = tid >> 4, col = (tid & 15) * 4;
        stf4(&hp[ci * RS + 4 + col], hv);
    }
    const int ch = tid >> 4, f0 = (tid & 15) * 4;
    float4 cc = ldf4(&cin[b * 2048 + ch * 64 + f0]);
    const float bi = bs[ch], bf = bs[32 + ch], bo = bs[64 + ch], bg = bs[96 + ch];
    const float4 z4 = make_float4(0.f,0.f,0.f,0.f);

    float4 nx = ldf4(&seq[(size_t)b * 2048 + tid * 4]);

#pragma unroll 1
    for (int t = 0; t < T_; ++t) {
        {
            int ci = tid >> 4, col = (tid & 15) * 4;
            stf4(&xin[ci * RS + 4 + col], nx);
        }
        __syncthreads();
        if (t + 1 < T_)
            nx = ldf4(&seq[((size_t)(t + 1) * B_ + b) * 2048 + tid * 4]);
        float4 ai = z4, af = z4, ao = z4, ag = z4;
#pragma unroll 1
        for (int rr = 0; rr < 32; ++rr)
            rowacc4<128>(&xin[rr * RS + 4 + f0], wl + (rr * 3) * 128 + ch * 4, ai, af, ao, ag);
#pragma unroll 1
        for (int rr = 0; rr < 32; ++rr)
            rowacc4<128>(&hp[rr * RS + 4 + f0], wl + ((32 + rr) * 3) * 128 + ch * 4, ai, af, ao, ag);
        float4 hn = gate4(ai, af, ao, ag, bi, bf, bo, bg, cc);
        __syncthreads();
        stf4(&hp[ch * RS + 4 + f0], hn);
        stf4(&seq[((size_t)t * B_ + b) * 2048 + ch * 64 + f0], hn);
    }
}

__global__ __launch_bounds__(512, 1) void dec1_fb(
    const float* __restrict__ w, const float* __restrict__ bias,
    const float* __restrict__ seq,
    const float* __restrict__ hin, const float* __restrict__ cin,
    const float* __restrict__ fw, const float* __restrict__ fb,
    float* __restrict__ out)
{
    __shared__ float wl[144 * 64];
    __shared__ float bs[64];
    __shared__ float xin[32 * RS];
    __shared__ float hp[16 * RS];
    __shared__ float fcw[16];
    __shared__ float fcb;

    const int tid = threadIdx.x;
    const int b = blockIdx.x;

    for (int idx = tid; idx < 144 * 64; idx += 512) {
        int k = idx >> 6, rr = idx & 63;
        int ch = rr >> 2, g = rr & 3;
        int ci = k / 3, d = k - ci * 3;
        wl[idx] = w[((g * 16 + ch) * 48 + ci) * 9 + d * 3 + 1];
    }
    if (tid < 64) bs[tid] = bias[tid];
    if (tid < 16) fcw[tid] = fw[tid];
    if (tid == 16) fcb = fb[0];
    for (int i = tid; i < 32 * RS; i += 512) xin[i] = 0.f;
    for (int i = tid; i < 16 * RS; i += 512) hp[i] = 0.f;
    __syncthreads();
    {
        const float* hs = &hin[b * 1024 + tid * 2];
        float2 hv = *reinterpret_cast<const float2*>(hs);
        int ci = tid >> 5, col = (tid & 31) * 2;
        *reinterpret_cast<float2*>(&hp[ci * RS + 4 + col]) = hv;
    }
    const int ch = tid >> 5, f0 = (tid & 31) * 2;
    float2 cc = *reinterpret_cast<const float2*>(&cin[b * 1024 + ch * 64 + f0]);
    const float bi = bs[ch], bf = bs[16 + ch], bo = bs[32 + ch], bg = bs[48 + ch];
    const float2 z2 = make_float2(0.f,0.f);
    float4 nx = ldf4(&seq[(size_t)b * 2048 + tid * 4]);
    __syncthreads();

#pragma unroll 1
    for (int t = 0; t < T_; ++t) {
        {
            int ci = tid >> 4, col = (tid & 15) * 4;
            stf4(&xin[ci * RS + 4 + col], nx);
        }
        __syncthreads();
        if (t + 1 < T_)
            nx = ldf4(&seq[((size_t)(t + 1) * B_ + b) * 2048 + tid * 4]);

        float2 ai = z2, af = z2, ao = z2, ag = z2;
#pragma unroll 1
        for (int rr = 0; rr < 32; ++rr)
            rowacc2<64>(&xin[rr * RS + 4 + f0], wl + (rr * 3) * 64 + ch * 4, ai, af, ao, ag);
#pragma unroll 1
        for (int rr = 0; rr < 16; ++rr)
            rowacc2<64>(&hp[rr * RS + 4 + f0], wl + ((32 + rr) * 3) * 64 + ch * 4, ai, af, ao, ag);

        float2 hh;
        hh.x = gate1(ai.x + bi, af.x + bf, ao.x + bo, ag.x + bg, cc.x);
        hh.y = gate1(ai.y + bi, af.y + bf, ao.y + bo, ag.y + bg, cc.y);
        __syncthreads();
        *reinterpret_cast<float2*>(&hp[ch * RS + 4 + f0]) = hh;
        __syncthreads();

        if (tid < 64) {
            float a = fcb;
#pragma unroll
            for (int k2 = 0; k2 < 16; ++k2)
                a = fmaf(fcw[k2], hp[k2 * RS + 4 + tid], a);
            out[(b * T_ + t) * 64 + tid] = a;
        }
    }
}

// ---------------------------------------------------------------------------
extern "C" void kernel_launch(void* const* d_in, const int* in_sizes, int n_in,
                              void* d_out, int out_size, void* d_ws, size_t ws_size,
                              hipStream_t stream)
{
    (void)in_sizes; (void)n_in; (void)out_size;
    const float* x   = (const float*)d_in[0];
    const float* ew0 = (const float*)d_in[1];
    const float* eb0 = (const float*)d_in[2];
    const float* ew1 = (const float*)d_in[3];
    const float* eb1 = (const float*)d_in[4];
    const float* dw0 = (const float*)d_in[5];
    const float* db0 = (const float*)d_in[6];
    const float* dw1 = (const float*)d_in[7];
    const float* db1 = (const float*)d_in[8];
    const float* fw  = (const float*)d_in[9];
    const float* fb  = (const float*)d_in[10];
    float* out = (float*)d_out;

    float* ws  = (float*)d_ws;
    size_t off = 0;
    float* seq = ws + off; off += (size_t)T_ * B_ * 2048;
    float* h1f = ws + off; off += (size_t)B_ * 1024;
    float* c1f = ws + off; off += (size_t)B_ * 1024;
    float* h2f = ws + off; off += (size_t)B_ * 2048;
    float* c2f = ws + off; off += (size_t)B_ * 2048;
    float* hd0 = ws + off; off += (size_t)B_ * 2048;
    float* cd0 = ws + off; off += (size_t)B_ * 2048;
    float* hd1 = ws + off; off += (size_t)B_ * 1024;
    float* cd1 = ws + off; off += (size_t)B_ * 1024;
    float* comm = ws + off; off += 32768 + 16384 + 8192;   // enc | dec0 | dec1
    int*   flg  = (int*)(ws + off); off += 1024;           // enc[0..255] dec[256..511]
    float* zx  = ws + off;

    float* commD0 = comm + 32768;
    float* commD1 = comm + 32768 + 16384;

    size_t availf = (ws_size / 4 > off) ? (ws_size / 4 - off) : 0;
    int TC = 0;
    if      (availf >= (size_t)100 * B_ * 8192) TC = 100;
    else if (availf >= (size_t)50  * B_ * 8192) TC = 50;
    else if (availf >= (size_t)25  * B_ * 8192) TC = 25;
    else if (availf >= (size_t)10  * B_ * 8192) TC = 10;

    hipMemsetAsync(flg, 0, 512 * sizeof(int), stream);
    enc_kernel<<<256, 1024, 0, stream>>>(x, ew0, eb0, ew1, eb1, seq,
                                         h1f, c1f, h2f, c2f, comm, flg);

    if (TC > 0) {
        for (int t0 = 0; t0 < T_; t0 += TC) {
            int tn = (t0 + TC <= T_) ? TC : (T_ - t0);
            int lastc = (t0 + tn >= T_) ? 1 : 0;
            int nchunks = (tn + XTB - 1) / XTB;
            xconv0_kernel<<<nchunks * B_, 256, 0, stream>>>(seq, dw0, zx, t0, tn);
            decg<<<256, 1024, 0, stream>>>(
                dw0, db0, dw1, db1, zx,
                t0 == 0 ? h2f : hd0, t0 == 0 ? c2f : cd0,
                t0 == 0 ? h1f : hd1, t0 == 0 ? c1f : cd1,
                hd0, cd0, hd1, cd1,
                fw, fb, out, commD0, commD1, flg + 256, t0, tn, lastc);
        }
    } else {
        dec0_fb<<<B_, 512, 0, stream>>>(dw0, db0, seq, h2f, c2f);
        dec1_fb<<<B_, 512, 0, stream>>>(dw1, db1, seq, h1f, c1f, fw, fb, out);
    }
}